// Round 6
// baseline (640.725 us; speedup 1.0000x reference)
//
#include <hip/hip_runtime.h>
#include <hip/hip_bf16.h>
#include <stdint.h>

typedef __attribute__((ext_vector_type(8))) short short8;
typedef __attribute__((ext_vector_type(8))) uint16_t ushort8;
typedef __attribute__((ext_vector_type(4))) float floatx4;

#define TK 64   // K elems staged per barrier pair (legacy kernel)

// ---------- helpers ----------

__device__ __forceinline__ uint16_t f2bf_bits(float f) {
    uint32_t u = __builtin_bit_cast(uint32_t, f);
    u += 0x7FFFu + ((u >> 16) & 1u);
    return (uint16_t)(u >> 16);
}

__device__ __forceinline__ void async_copy16(const void* g, void* l) {
    // global -> LDS direct copy, 16B/lane; LDS dest = wave-uniform base + lane*16
    auto gp = (const __attribute__((address_space(1))) uint32_t*)(uintptr_t)g;
    auto lp = (__attribute__((address_space(3))) uint32_t*)(uint32_t)(uintptr_t)l;
    __builtin_amdgcn_global_load_lds(gp, lp, 16, 0, 0);
}

// ---------- fp32 -> bf16 conversion kernels ----------

__global__ void cvt8(const float* __restrict__ src, uint16_t* __restrict__ dst, int n) {
    int i = (blockIdx.x * 256 + threadIdx.x) * 8;
    if (i >= n) return;
    floatx4 a = *(const floatx4*)(src + i);
    floatx4 b = *(const floatx4*)(src + i + 4);
    ushort8 o;
#pragma unroll
    for (int k = 0; k < 4; k++) {
        o[k]     = f2bf_bits(a[k]);
        o[k + 4] = f2bf_bits(b[k]);
    }
    *(ushort8*)(dst + i) = o;
}

// W2 [51][2048] fp32 -> [64][2048] bf16, rows >= 51 zeroed
__global__ void cvt_pad_w2(const float* __restrict__ src, uint16_t* __restrict__ dst) {
    int i = (blockIdx.x * 256 + threadIdx.x) * 8;   // over 64*2048
    int row = i >> 11;
    ushort8 o;
    if (row < 51) {
        floatx4 a = *(const floatx4*)(src + i);
        floatx4 b = *(const floatx4*)(src + i + 4);
#pragma unroll
        for (int k = 0; k < 4; k++) {
            o[k]     = f2bf_bits(a[k]);
            o[k + 4] = f2bf_bits(b[k]);
        }
    } else {
#pragma unroll
        for (int k = 0; k < 8; k++) o[k] = 0;
    }
    *(ushort8*)(dst + i) = o;
}

// ---------- legacy small-tile GEMM (kept for layer 2: N=64) ----------
// C[m,n] = act( sum_k A[m,k]*W[n,k] + bias[n] )

template <int MI, int NJ, bool RELU, bool OUTF32>
__global__ __launch_bounds__(256, 2)
void gemm_bt(const uint16_t* __restrict__ A,
             const uint16_t* __restrict__ W,
             const float* __restrict__ bias,
             void* __restrict__ out,
             int M, int N, int K, int ldc, int nstore)
{
    constexpr int TMv = MI * 32;
    constexpr int TNv = NJ * 32;
    constexpr int ACH = TMv / 32;
    constexpr int BCH = TNv / 32;

    __shared__ alignas(16) uint16_t sA[TMv * TK];
    __shared__ alignas(16) uint16_t sB[TNv * TK];

    const int tid  = threadIdx.x;
    const int wave = tid >> 6;
    const int lane = tid & 63;

    const int f   = blockIdx.x;
    const int xcd = f & 7;
    const int loc = f >> 3;
    const int per = (int)gridDim.x >> 3;
    const int nt  = N / TNv;
    const int n_t = loc % nt;
    const int m_t = xcd * (per / nt) + loc / nt;
    const int n0 = n_t * TNv;
    const int m0 = m_t * TMv;

    floatx4 acc[MI][NJ];
    const floatx4 zero = {0.f, 0.f, 0.f, 0.f};
#pragma unroll
    for (int i = 0; i < MI; i++)
#pragma unroll
        for (int j = 0; j < NJ; j++) acc[i][j] = zero;

    const int wr = (wave >> 1) * MI * 16;
    const int wc = (wave & 1) * NJ * 16;

    const int sr   = lane >> 3;
    const int scol = ((lane & 7) ^ sr) * 8;

    const uint16_t* ap[ACH];
    const uint16_t* bp[BCH];
#pragma unroll
    for (int t = 0; t < ACH; t++)
        ap[t] = A + (size_t)(m0 + (wave + 4 * t) * 8 + sr) * K + scol;
#pragma unroll
    for (int t = 0; t < BCH; t++)
        bp[t] = W + (size_t)(n0 + (wave + 4 * t) * 8 + sr) * K + scol;

    const int fm = lane & 15;
    const int fr = fm & 7;
    const int kgb = lane >> 4;

    const int niter = K / TK;
    for (int it = 0; it < niter; it++) {
#pragma unroll
        for (int t = 0; t < ACH; t++) {
            async_copy16(ap[t], sA + (wave + 4 * t) * 512);
            ap[t] += TK;
        }
#pragma unroll
        for (int t = 0; t < BCH; t++) {
            async_copy16(bp[t], sB + (wave + 4 * t) * 512);
            bp[t] += TK;
        }
        __syncthreads();

#pragma unroll
        for (int kk = 0; kk < 2; kk++) {
            const int slot = ((kgb + 4 * kk) ^ fr) * 8;
            short8 af[MI], bfr[NJ];
#pragma unroll
            for (int i = 0; i < MI; i++)
                af[i] = *(const short8*)(sA + (wr + i * 16 + fm) * TK + slot);
#pragma unroll
            for (int j = 0; j < NJ; j++)
                bfr[j] = *(const short8*)(sB + (wc + j * 16 + fm) * TK + slot);
#pragma unroll
            for (int i = 0; i < MI; i++)
#pragma unroll
                for (int j = 0; j < NJ; j++)
                    acc[i][j] = __builtin_amdgcn_mfma_f32_16x16x32_bf16(af[i], bfr[j], acc[i][j], 0, 0, 0);
        }
        __syncthreads();
    }

    const int cr = (lane >> 4) * 4;
    const int cc = lane & 15;
#pragma unroll
    for (int i = 0; i < MI; i++) {
        const int gmb = m0 + wr + i * 16 + cr;
#pragma unroll
        for (int j = 0; j < NJ; j++) {
            const int gn = n0 + wc + j * 16 + cc;
            if (gn < nstore) {
                const float bv = bias[gn];
#pragma unroll
                for (int r = 0; r < 4; r++) {
                    float v = acc[i][j][r] + bv;
                    if (RELU) v = fmaxf(v, 0.f);
                    const size_t idx = (size_t)(gmb + r) * ldc + gn;
                    if (OUTF32) ((float*)out)[idx] = v;
                    else        ((uint16_t*)out)[idx] = f2bf_bits(v);
                }
            }
        }
    }
}

// ---------- 256x256 GEMM, 1 barrier / K-tile, reads-before-MFMA overlap ----------
// 8 waves (2M x 4N), 512 threads, BK=64, LDS 128 KiB (2 bufs x (A 256x64 + B 256x64)).
// K-tile T lives in buf(T&1). Fragment ping-pong: aP holds a0(T) (read one
// segment early), aQ holds a1(T); b0/b1 carried within the tile.
//   SEG1: issue reads {b0,b1,a1}(T) -> MFMA q00(aP,b0), q01(aP,b1)
//         -> lgkm0+vmcnt0 -> s_barrier
//   SEG2: stage tile T+2 -> read a0(T+1)->aP from other buf
//         -> MFMA q10(aQ,b0), q11(aQ,b1)
// Ordering proof:
//  - stage(X) issued at (X-2)'s SEG2; drained by vmcnt(0) at (X-1)'s SEG1
//    + barrier => visible before a0(X) read at (X-1)'s SEG2 and all X reads.
//  - stages into a region always follow the barrier after that region's last
//    reads (lgkm0 pre-barrier drains them).
// STAGING COVERAGE (r5 bug fix): each 256x64 region = 32 chunks of 1KB; each
// wave stages 4 chunks {w, w+8, w+16, w+24} = rows {8w,64+8w,128+8w,192+8w}.
// 8 waves x 4 copies x 1KB = 32KB = full region.  (r5 had 2 copies -> half
// the region unstaged -> absmax 15.7.)
// 24 ds_read_b128 / wave / K-tile (minimum); 1 barrier / K-tile.

#define SCHED0 __builtin_amdgcn_sched_barrier(0)

#define LOAD_AF(SA, QM, DST) do { \
    const uint16_t* _p = (SA) + (QM) * 8192 + aoff; \
    _Pragma("unroll") \
    for (int kk = 0; kk < 2; kk++) { \
      const int sl = ((kgb + 4 * kk) ^ fr) * 8; \
      _Pragma("unroll") \
      for (int mi = 0; mi < 4; mi++) \
        DST[mi][kk] = *(const short8*)(_p + mi * 1024 + sl); \
    } } while (0)

#define LOAD_BF(SB, QN, BF) do { \
    const uint16_t* _p = (SB) + (QN) * 8192 + boff; \
    _Pragma("unroll") \
    for (int kk = 0; kk < 2; kk++) { \
      const int sl = ((kgb + 4 * kk) ^ fr) * 8; \
      _Pragma("unroll") \
      for (int nj = 0; nj < 2; nj++) \
        BF[nj][kk] = *(const short8*)(_p + nj * 1024 + sl); \
    } } while (0)

#define MFMA_CL(QM, QN, AF, BF) \
    __builtin_amdgcn_s_setprio(1); \
    _Pragma("unroll") \
    for (int kk = 0; kk < 2; kk++) \
      _Pragma("unroll") \
      for (int mi = 0; mi < 4; mi++) \
        _Pragma("unroll") \
        for (int nj = 0; nj < 2; nj++) \
          acc[QM][QN][mi][nj] = __builtin_amdgcn_mfma_f32_16x16x32_bf16( \
              AF[mi][kk], BF[nj][kk], acc[QM][QN][mi][nj], 0, 0, 0); \
    __builtin_amdgcn_s_setprio(0); \
    SCHED0;

// One K-tile. SAC/SBC: current buf; SAN: other buf (next tile's A).
// STG: stage tile TT+2 into current buf. NEXT: prefetch a0(TT+1)->aP.
#define TILE_BODY(SAC, SBC, SAN, TT, STG, NEXT) \
    /* SEG1: reads issue first, MFMA overlaps them */ \
    LOAD_BF(SBC, 0, b0); \
    LOAD_BF(SBC, 1, b1); \
    LOAD_AF(SAC, 1, aQ); \
    SCHED0; \
    MFMA_CL(0, 0, aP, b0); \
    MFMA_CL(0, 1, aP, b1); \
    asm volatile("s_waitcnt vmcnt(0) lgkmcnt(0)" ::: "memory"); \
    SCHED0; \
    __builtin_amdgcn_s_barrier(); \
    SCHED0; \
    /* SEG2: stage + next-tile a0 prefetch overlap the q10/q11 cluster */ \
    if (STG) { stB((TT) + 2, SBC); stA((TT) + 2, SAC); } \
    if (NEXT) LOAD_AF(SAN, 0, aP); \
    SCHED0; \
    MFMA_CL(1, 0, aQ, b0); \
    MFMA_CL(1, 1, aQ, b1);

template <bool RELU, bool OUTF32>
__global__ __launch_bounds__(512, 2)
void gemm256(const uint16_t* __restrict__ A,
             const uint16_t* __restrict__ W,
             const float* __restrict__ bias,
             void* __restrict__ out,
             int K, int N, int ldc, int nstore)
{
    extern __shared__ uint16_t smem[];   // 65536 uint16 = 128 KiB
    uint16_t* sA0 = smem;                // A buf0 (even K-tiles)
    uint16_t* sA1 = smem + 16384;
    uint16_t* sB0 = smem + 32768;
    uint16_t* sB1 = smem + 49152;

    const int tid  = threadIdx.x;
    const int wave = tid >> 6;          // 0..7
    const int lane = tid & 63;
    const int wm2  = wave >> 2;         // 0..1
    const int wn2  = wave & 3;          // 0..3

    // XCD-aware tile assignment (grid % 8 == 0, per % ntn == 0)
    const int f   = blockIdx.x;
    const int xcd = f & 7;
    const int loc = f >> 3;
    const int per = (int)gridDim.x >> 3;
    const int ntn = N / 256;
    const int n_t = loc % ntn;
    const int m_t = xcd * (per / ntn) + loc / ntn;
    const int m0 = m_t * 256;
    const int n0 = n_t * 256;

    floatx4 acc[2][2][4][2];
    const floatx4 zero = {0.f, 0.f, 0.f, 0.f};
#pragma unroll
    for (int qm = 0; qm < 2; qm++)
#pragma unroll
    for (int qn = 0; qn < 2; qn++)
#pragma unroll
    for (int mi = 0; mi < 4; mi++)
#pragma unroll
    for (int nj = 0; nj < 2; nj++) acc[qm][qn][mi][nj] = zero;

    // staging addressing: 1KB chunk = 8 rows x 64 cols; slot s of row r holds
    // global k-group s ^ (r&7)  (bank-conflict-free frag reads; measured 0-conflict)
    const int srow = lane >> 3;
    const int scol = ((lane & 7) ^ srow) * 8;
    const uint16_t* pA = A + (size_t)(m0 + wave * 8 + srow) * K + scol;
    const uint16_t* pB = W + (size_t)(n0 + wave * 8 + srow) * K + scol;

    // full-region staging: 4 chunks/wave at row offsets 0,64,128,192
    auto stA = [&](int kt, uint16_t* buf) {
        const uint16_t* p = pA + (size_t)kt * 64;
        async_copy16(p,                    buf + wave * 512);
        async_copy16(p + (size_t)64  * K,  buf + 4096  + wave * 512);
        async_copy16(p + (size_t)128 * K,  buf + 8192  + wave * 512);
        async_copy16(p + (size_t)192 * K,  buf + 12288 + wave * 512);
    };
    auto stB = [&](int kt, uint16_t* buf) {
        const uint16_t* p = pB + (size_t)kt * 64;
        async_copy16(p,                    buf + wave * 512);
        async_copy16(p + (size_t)64  * K,  buf + 4096  + wave * 512);
        async_copy16(p + (size_t)128 * K,  buf + 8192  + wave * 512);
        async_copy16(p + (size_t)192 * K,  buf + 12288 + wave * 512);
    };

    // fragment addressing
    const int fm  = lane & 15;
    const int fr  = fm & 7;
    const int kgb = lane >> 4;                 // 0..3
    const int aoff = (wm2 * 64 + fm) * 64;
    const int boff = (wn2 * 32 + fm) * 64;

    // fragment registers
    short8 aP[4][2];     // a0 of current tile (prefetched one segment early)
    short8 aQ[4][2];     // a1 of current tile
    short8 b0[2][2];     // B half 0 (lives whole tile)
    short8 b1[2][2];     // B half 1 (lives whole tile)

    // ---- prologue: stage tile0 + tile1; wait tile0; pre-read a0(0) ----
    stB(0, sB0);
    stA(0, sA0);
    stB(1, sB1);
    stA(1, sA1);
    asm volatile("s_waitcnt vmcnt(8)" ::: "memory");   // tile0 (8 copies) landed
    __builtin_amdgcn_s_barrier();
    SCHED0;
    LOAD_AF(sA0, 0, aP);    // a0(tile0); drains at first SEG1's compiler waits

    const int niter = K / 64;
    for (int it = 0; it < (niter - 2) / 2; ++it) {
        const int T = 2 * it;
        TILE_BODY(sA0, sB0, sA1, T,     true, true);
        TILE_BODY(sA1, sB1, sA0, T + 1, true, true);
    }
    // peeled tail: no further staging; last tile has no next-A prefetch
    TILE_BODY(sA0, sB0, sA1, niter - 2, false, true);
    TILE_BODY(sA1, sB1, sA0, niter - 1, false, false);

    // ---- epilogue: C/D layout col = lane&15, row = (lane>>4)*4 + reg ----
    const int cr = (lane >> 4) * 4;
    const int cc = lane & 15;
#pragma unroll
    for (int qm = 0; qm < 2; qm++)
#pragma unroll
    for (int mi = 0; mi < 4; mi++) {
        const int gm = m0 + qm * 128 + wm2 * 64 + mi * 16 + cr;
#pragma unroll
        for (int qn = 0; qn < 2; qn++)
#pragma unroll
        for (int nj = 0; nj < 2; nj++) {
            const int gn = n0 + qn * 128 + wn2 * 32 + nj * 16 + cc;
            if (gn < nstore) {
                const float bv = bias[gn];
#pragma unroll
                for (int r = 0; r < 4; r++) {
                    float v = acc[qm][qn][mi][nj][r] + bv;
                    if (RELU) v = fmaxf(v, 0.f);
                    const size_t idx = (size_t)(gm + r) * ldc + gn;
                    if (OUTF32) ((float*)out)[idx] = v;
                    else        ((uint16_t*)out)[idx] = f2bf_bits(v);
                }
            }
        }
    }
}

// ---------- launch ----------

extern "C" void kernel_launch(void* const* d_in, const int* in_sizes, int n_in,
                              void* d_out, int out_size, void* d_ws, size_t ws_size,
                              hipStream_t stream) {
    (void)in_sizes; (void)n_in; (void)out_size; (void)ws_size;
    const float* X  = (const float*)d_in[1];
    const float* W0 = (const float*)d_in[3];
    const float* b0 = (const float*)d_in[4];
    const float* W1 = (const float*)d_in[5];
    const float* b1 = (const float*)d_in[6];
    const float* W2 = (const float*)d_in[7];
    const float* b2 = (const float*)d_in[8];

    const int M = 16384;     // 16 batches * 1024 pairs

    static bool attr_done = false;
    if (!attr_done) {
        (void)hipFuncSetAttribute((const void*)gemm256<true, false>,
                                  hipFuncAttributeMaxDynamicSharedMemorySize, 131072);
        attr_done = true;
    }

    char* w = (char*)d_ws;
    uint16_t* X0  = (uint16_t*)w; w += (size_t)M * 1024 * 2;
    uint16_t* X1  = (uint16_t*)w; w += (size_t)M * 2048 * 2;
    uint16_t* X2  = (uint16_t*)w; w += (size_t)M * 2048 * 2;
    uint16_t* W0b = (uint16_t*)w; w += (size_t)2048 * 1024 * 2;
    uint16_t* W1b = (uint16_t*)w; w += (size_t)2048 * 2048 * 2;
    uint16_t* W2b = (uint16_t*)w; w += (size_t)64 * 2048 * 2;

    cvt8<<<M * 1024 / 8 / 256, 256, 0, stream>>>(X, X0, M * 1024);
    cvt8<<<2048 * 1024 / 8 / 256, 256, 0, stream>>>(W0, W0b, 2048 * 1024);
    cvt8<<<2048 * 2048 / 8 / 256, 256, 0, stream>>>(W1, W1b, 2048 * 2048);
    cvt_pad_w2<<<64 * 2048 / 8 / 256, 256, 0, stream>>>(W2, W2b);

    // layer 0: [16384,1024] x [2048,1024]^T -> relu -> bf16; 256x256
    gemm256<true, false><<<dim3((M / 256) * (2048 / 256)), 512, 131072, stream>>>(
        X0, W0b, b0, X1, 1024, 2048, 2048, 2048);
    // layer 1: [16384,2048] x [2048,2048]^T -> relu -> bf16; 256x256
    gemm256<true, false><<<dim3((M / 256) * (2048 / 256)), 512, 131072, stream>>>(
        X1, W1b, b1, X2, 2048, 2048, 2048, 2048);
    // layer 2: [16384,2048] x [64(pad 51),2048]^T -> fp32; 32x64 tiles, 512 blocks
    gemm_bt<1, 2, false, true><<<dim3(M / 32), 256, 0, stream>>>(
        X2, W2b, b2, d_out, M, 64, 2048, 51, 51);
}

// Round 7
// 351.016 us; speedup vs baseline: 1.8253x; 1.8253x over previous
//
#include <hip/hip_runtime.h>
#include <hip/hip_bf16.h>
#include <stdint.h>

typedef __attribute__((ext_vector_type(8))) short short8;
typedef __attribute__((ext_vector_type(8))) uint16_t ushort8;
typedef __attribute__((ext_vector_type(4))) float floatx4;

#define TK 64   // K elems staged per barrier pair (legacy kernel)

// ---------- helpers ----------

__device__ __forceinline__ uint16_t f2bf_bits(float f) {
    uint32_t u = __builtin_bit_cast(uint32_t, f);
    u += 0x7FFFu + ((u >> 16) & 1u);
    return (uint16_t)(u >> 16);
}

__device__ __forceinline__ void async_copy16(const void* g, void* l) {
    // global -> LDS direct copy, 16B/lane; LDS dest = wave-uniform base + lane*16
    auto gp = (const __attribute__((address_space(1))) uint32_t*)(uintptr_t)g;
    auto lp = (__attribute__((address_space(3))) uint32_t*)(uint32_t)(uintptr_t)l;
    __builtin_amdgcn_global_load_lds(gp, lp, 16, 0, 0);
}

// ---------- fp32 -> bf16 conversion kernels ----------

__global__ void cvt8(const float* __restrict__ src, uint16_t* __restrict__ dst, int n) {
    int i = (blockIdx.x * 256 + threadIdx.x) * 8;
    if (i >= n) return;
    floatx4 a = *(const floatx4*)(src + i);
    floatx4 b = *(const floatx4*)(src + i + 4);
    ushort8 o;
#pragma unroll
    for (int k = 0; k < 4; k++) {
        o[k]     = f2bf_bits(a[k]);
        o[k + 4] = f2bf_bits(b[k]);
    }
    *(ushort8*)(dst + i) = o;
}

// W2 [51][2048] fp32 -> [64][2048] bf16, rows >= 51 zeroed
__global__ void cvt_pad_w2(const float* __restrict__ src, uint16_t* __restrict__ dst) {
    int i = (blockIdx.x * 256 + threadIdx.x) * 8;   // over 64*2048
    int row = i >> 11;
    ushort8 o;
    if (row < 51) {
        floatx4 a = *(const floatx4*)(src + i);
        floatx4 b = *(const floatx4*)(src + i + 4);
#pragma unroll
        for (int k = 0; k < 4; k++) {
            o[k]     = f2bf_bits(a[k]);
            o[k + 4] = f2bf_bits(b[k]);
        }
    } else {
#pragma unroll
        for (int k = 0; k < 8; k++) o[k] = 0;
    }
    *(ushort8*)(dst + i) = o;
}

// ---------- legacy small-tile GEMM (kept for layer 2: N=64) ----------
// C[m,n] = act( sum_k A[m,k]*W[n,k] + bias[n] )

template <int MI, int NJ, bool RELU, bool OUTF32>
__global__ __launch_bounds__(256, 2)
void gemm_bt(const uint16_t* __restrict__ A,
             const uint16_t* __restrict__ W,
             const float* __restrict__ bias,
             void* __restrict__ out,
             int M, int N, int K, int ldc, int nstore)
{
    constexpr int TMv = MI * 32;
    constexpr int TNv = NJ * 32;
    constexpr int ACH = TMv / 32;
    constexpr int BCH = TNv / 32;

    __shared__ alignas(16) uint16_t sA[TMv * TK];
    __shared__ alignas(16) uint16_t sB[TNv * TK];

    const int tid  = threadIdx.x;
    const int wave = tid >> 6;
    const int lane = tid & 63;

    const int f   = blockIdx.x;
    const int xcd = f & 7;
    const int loc = f >> 3;
    const int per = (int)gridDim.x >> 3;
    const int nt  = N / TNv;
    const int n_t = loc % nt;
    const int m_t = xcd * (per / nt) + loc / nt;
    const int n0 = n_t * TNv;
    const int m0 = m_t * TMv;

    floatx4 acc[MI][NJ];
    const floatx4 zero = {0.f, 0.f, 0.f, 0.f};
#pragma unroll
    for (int i = 0; i < MI; i++)
#pragma unroll
        for (int j = 0; j < NJ; j++) acc[i][j] = zero;

    const int wr = (wave >> 1) * MI * 16;
    const int wc = (wave & 1) * NJ * 16;

    const int sr   = lane >> 3;
    const int scol = ((lane & 7) ^ sr) * 8;

    const uint16_t* ap[ACH];
    const uint16_t* bp[BCH];
#pragma unroll
    for (int t = 0; t < ACH; t++)
        ap[t] = A + (size_t)(m0 + (wave + 4 * t) * 8 + sr) * K + scol;
#pragma unroll
    for (int t = 0; t < BCH; t++)
        bp[t] = W + (size_t)(n0 + (wave + 4 * t) * 8 + sr) * K + scol;

    const int fm = lane & 15;
    const int fr = fm & 7;
    const int kgb = lane >> 4;

    const int niter = K / TK;
    for (int it = 0; it < niter; it++) {
#pragma unroll
        for (int t = 0; t < ACH; t++) {
            async_copy16(ap[t], sA + (wave + 4 * t) * 512);
            ap[t] += TK;
        }
#pragma unroll
        for (int t = 0; t < BCH; t++) {
            async_copy16(bp[t], sB + (wave + 4 * t) * 512);
            bp[t] += TK;
        }
        __syncthreads();

#pragma unroll
        for (int kk = 0; kk < 2; kk++) {
            const int slot = ((kgb + 4 * kk) ^ fr) * 8;
            short8 af[MI], bfr[NJ];
#pragma unroll
            for (int i = 0; i < MI; i++)
                af[i] = *(const short8*)(sA + (wr + i * 16 + fm) * TK + slot);
#pragma unroll
            for (int j = 0; j < NJ; j++)
                bfr[j] = *(const short8*)(sB + (wc + j * 16 + fm) * TK + slot);
#pragma unroll
            for (int i = 0; i < MI; i++)
#pragma unroll
                for (int j = 0; j < NJ; j++)
                    acc[i][j] = __builtin_amdgcn_mfma_f32_16x16x32_bf16(af[i], bfr[j], acc[i][j], 0, 0, 0);
        }
        __syncthreads();
    }

    const int cr = (lane >> 4) * 4;
    const int cc = lane & 15;
#pragma unroll
    for (int i = 0; i < MI; i++) {
        const int gmb = m0 + wr + i * 16 + cr;
#pragma unroll
        for (int j = 0; j < NJ; j++) {
            const int gn = n0 + wc + j * 16 + cc;
            if (gn < nstore) {
                const float bv = bias[gn];
#pragma unroll
                for (int r = 0; r < 4; r++) {
                    float v = acc[i][j][r] + bv;
                    if (RELU) v = fmaxf(v, 0.f);
                    const size_t idx = (size_t)(gmb + r) * ldc + gn;
                    if (OUTF32) ((float*)out)[idx] = v;
                    else        ((uint16_t*)out)[idx] = f2bf_bits(v);
                }
            }
        }
    }
}

// ---------- 256x256 GEMM: 2 barriers / K-tile, r3 register budget ----------
// 8 waves (2M x 4N), 512 threads, BK=64, LDS 128 KiB (2 bufs x (A 256x64 + B 256x64)).
// Fragment regs EXACTLY as r3 (af 32 + b0 16 + b1 16 = 64; acc 128 in AGPR):
// r6's +32-reg ping-pong spilled (WRITE_SIZE 743MB) -> hard constraint: frags <= 64.
// K-tile T in buf(T&1):
//  Phase A: stage(T+1 -> other buf)  [issues early, lands under ~1.5 tiles of work]
//           read {a0->af, b0, b1}(cur buf); lgkm0; barrier; MFMA q00,q01
//  Phase B: read a1->af (in-place; WAR after q00/q01 issue, in-order safe);
//           lgkm0; vmcnt(0); barrier; MFMA q10,q11
// Ordering invariants:
//  - stage(T+1->bufY) at T.A follows T-1.B's lgkm0+barrier which drained bufY's
//    last reads (T-1.B reads a1 from bufY).
//  - vmcnt(0) BEFORE T.B's barrier: each wave waits its own stage(T+1) copies,
//    then the barrier publishes "all waves' stages landed" before T+1.A reads.
//    (vmcnt is per-wave; it must sit on the pre-barrier side.)
//  - stage copies were issued ~1.5 phases earlier than the vmcnt -> no stall.
// Pipe overlap: phase-A MFMA (after barrier) hides phase-B's 8 reads; phase-B
// MFMA hides T+1.A's 8 stage-issues + 16 reads. 2 barriers/tile vs r3's 4.

#define SCHED0 __builtin_amdgcn_sched_barrier(0)

#define LOAD_AF(SA, QM, DST) do { \
    const uint16_t* _p = (SA) + (QM) * 8192 + aoff; \
    _Pragma("unroll") \
    for (int kk = 0; kk < 2; kk++) { \
      const int sl = ((kgb + 4 * kk) ^ fr) * 8; \
      _Pragma("unroll") \
      for (int mi = 0; mi < 4; mi++) \
        DST[mi][kk] = *(const short8*)(_p + mi * 1024 + sl); \
    } } while (0)

#define LOAD_BF(SB, QN, BF) do { \
    const uint16_t* _p = (SB) + (QN) * 8192 + boff; \
    _Pragma("unroll") \
    for (int kk = 0; kk < 2; kk++) { \
      const int sl = ((kgb + 4 * kk) ^ fr) * 8; \
      _Pragma("unroll") \
      for (int nj = 0; nj < 2; nj++) \
        BF[nj][kk] = *(const short8*)(_p + nj * 1024 + sl); \
    } } while (0)

// lgkm0 then barrier (reads pinned above; MFMA after)
#define PH_SYNC \
    SCHED0; \
    asm volatile("s_waitcnt lgkmcnt(0)" ::: "memory"); \
    SCHED0; \
    __builtin_amdgcn_s_barrier(); \
    SCHED0;

// lgkm0 + vmcnt(0) then barrier (publishes staged tile to all waves)
#define PH_SYNC_VM \
    SCHED0; \
    asm volatile("s_waitcnt vmcnt(0) lgkmcnt(0)" ::: "memory"); \
    SCHED0; \
    __builtin_amdgcn_s_barrier(); \
    SCHED0;

#define MFMA_CL(QM, QN, AF, BF) \
    __builtin_amdgcn_s_setprio(1); \
    _Pragma("unroll") \
    for (int kk = 0; kk < 2; kk++) \
      _Pragma("unroll") \
      for (int mi = 0; mi < 4; mi++) \
        _Pragma("unroll") \
        for (int nj = 0; nj < 2; nj++) \
          acc[QM][QN][mi][nj] = __builtin_amdgcn_mfma_f32_16x16x32_bf16( \
              AF[mi][kk], BF[nj][kk], acc[QM][QN][mi][nj], 0, 0, 0); \
    __builtin_amdgcn_s_setprio(0); \
    SCHED0;

// One K-tile. SAc/SBc: this tile's buffers; SAo/SBo: other buffers.
// STG: stage tile TT+1 into the other buffers.
#define TILE_BODY(SAc, SBc, SAo, SBo, TT, STG) \
    /* Phase A */ \
    if (STG) { stB((TT) + 1, SBo); stA((TT) + 1, SAo); } \
    LOAD_AF(SAc, 0, af); \
    LOAD_BF(SBc, 0, b0); \
    LOAD_BF(SBc, 1, b1); \
    PH_SYNC; \
    MFMA_CL(0, 0, af, b0); \
    MFMA_CL(0, 1, af, b1); \
    /* Phase B */ \
    LOAD_AF(SAc, 1, af); \
    PH_SYNC_VM; \
    MFMA_CL(1, 0, af, b0); \
    MFMA_CL(1, 1, af, b1);

template <bool RELU, bool OUTF32>
__global__ __launch_bounds__(512, 2)
void gemm256(const uint16_t* __restrict__ A,
             const uint16_t* __restrict__ W,
             const float* __restrict__ bias,
             void* __restrict__ out,
             int K, int N, int ldc, int nstore)
{
    extern __shared__ uint16_t smem[];   // 65536 uint16 = 128 KiB
    uint16_t* sA0 = smem;                // A buf0 (even K-tiles)
    uint16_t* sA1 = smem + 16384;
    uint16_t* sB0 = smem + 32768;
    uint16_t* sB1 = smem + 49152;

    const int tid  = threadIdx.x;
    const int wave = tid >> 6;          // 0..7
    const int lane = tid & 63;
    const int wm2  = wave >> 2;         // 0..1
    const int wn2  = wave & 3;          // 0..3

    // XCD-aware tile assignment (grid % 8 == 0, per % ntn == 0)
    const int f   = blockIdx.x;
    const int xcd = f & 7;
    const int loc = f >> 3;
    const int per = (int)gridDim.x >> 3;
    const int ntn = N / 256;
    const int n_t = loc % ntn;
    const int m_t = xcd * (per / ntn) + loc / ntn;
    const int m0 = m_t * 256;
    const int n0 = n_t * 256;

    floatx4 acc[2][2][4][2];
    const floatx4 zero = {0.f, 0.f, 0.f, 0.f};
#pragma unroll
    for (int qm = 0; qm < 2; qm++)
#pragma unroll
    for (int qn = 0; qn < 2; qn++)
#pragma unroll
    for (int mi = 0; mi < 4; mi++)
#pragma unroll
    for (int nj = 0; nj < 2; nj++) acc[qm][qn][mi][nj] = zero;

    // staging addressing: 1KB chunk = 8 rows x 64 cols; slot s of row r holds
    // global k-group s ^ (r&7)  (bank-conflict-free frag reads; measured 0-conflict)
    const int srow = lane >> 3;
    const int scol = ((lane & 7) ^ srow) * 8;
    const uint16_t* pA = A + (size_t)(m0 + wave * 8 + srow) * K + scol;
    const uint16_t* pB = W + (size_t)(n0 + wave * 8 + srow) * K + scol;

    // full-region staging: 4 chunks/wave at row offsets 0,64,128,192 (32KB total)
    auto stA = [&](int kt, uint16_t* buf) {
        const uint16_t* p = pA + (size_t)kt * 64;
        async_copy16(p,                    buf + wave * 512);
        async_copy16(p + (size_t)64  * K,  buf + 4096  + wave * 512);
        async_copy16(p + (size_t)128 * K,  buf + 8192  + wave * 512);
        async_copy16(p + (size_t)192 * K,  buf + 12288 + wave * 512);
    };
    auto stB = [&](int kt, uint16_t* buf) {
        const uint16_t* p = pB + (size_t)kt * 64;
        async_copy16(p,                    buf + wave * 512);
        async_copy16(p + (size_t)64  * K,  buf + 4096  + wave * 512);
        async_copy16(p + (size_t)128 * K,  buf + 8192  + wave * 512);
        async_copy16(p + (size_t)192 * K,  buf + 12288 + wave * 512);
    };

    // fragment addressing
    const int fm  = lane & 15;
    const int fr  = fm & 7;
    const int kgb = lane >> 4;                 // 0..3
    const int aoff = (wm2 * 64 + fm) * 64;
    const int boff = (wn2 * 32 + fm) * 64;

    // fragment registers (r3 budget: 64 VGPRs total)
    short8 af[4][2];     // A frags for current QM half (reloaded in place)
    short8 b0[2][2];     // B half 0 (lives whole tile)
    short8 b1[2][2];     // B half 1 (lives whole tile)

    // ---- prologue: stage tile0; publish to all waves ----
    stB(0, sB0);
    stA(0, sA0);
    asm volatile("s_waitcnt vmcnt(0)" ::: "memory");
    __builtin_amdgcn_s_barrier();
    SCHED0;

    const int niter = K / 64;
    for (int it = 0; it < niter / 2 - 1; ++it) {
        TILE_BODY(sA0, sB0, sA1, sB1, 2 * it,     true);
        TILE_BODY(sA1, sB1, sA0, sB0, 2 * it + 1, true);
    }
    // peeled last pair: niter-2 stages the final tile; niter-1 stages nothing
    TILE_BODY(sA0, sB0, sA1, sB1, niter - 2, true);
    TILE_BODY(sA1, sB1, sA0, sB0, niter - 1, false);

    // ---- epilogue: C/D layout col = lane&15, row = (lane>>4)*4 + reg ----
    const int cr = (lane >> 4) * 4;
    const int cc = lane & 15;
#pragma unroll
    for (int qm = 0; qm < 2; qm++)
#pragma unroll
    for (int mi = 0; mi < 4; mi++) {
        const int gm = m0 + qm * 128 + wm2 * 64 + mi * 16 + cr;
#pragma unroll
        for (int qn = 0; qn < 2; qn++)
#pragma unroll
        for (int nj = 0; nj < 2; nj++) {
            const int gn = n0 + qn * 128 + wn2 * 32 + nj * 16 + cc;
            if (gn < nstore) {
                const float bv = bias[gn];
#pragma unroll
                for (int r = 0; r < 4; r++) {
                    float v = acc[qm][qn][mi][nj][r] + bv;
                    if (RELU) v = fmaxf(v, 0.f);
                    const size_t idx = (size_t)(gm + r) * ldc + gn;
                    if (OUTF32) ((float*)out)[idx] = v;
                    else        ((uint16_t*)out)[idx] = f2bf_bits(v);
                }
            }
        }
    }
}

// ---------- launch ----------

extern "C" void kernel_launch(void* const* d_in, const int* in_sizes, int n_in,
                              void* d_out, int out_size, void* d_ws, size_t ws_size,
                              hipStream_t stream) {
    (void)in_sizes; (void)n_in; (void)out_size; (void)ws_size;
    const float* X  = (const float*)d_in[1];
    const float* W0 = (const float*)d_in[3];
    const float* b0 = (const float*)d_in[4];
    const float* W1 = (const float*)d_in[5];
    const float* b1 = (const float*)d_in[6];
    const float* W2 = (const float*)d_in[7];
    const float* b2 = (const float*)d_in[8];

    const int M = 16384;     // 16 batches * 1024 pairs

    static bool attr_done = false;
    if (!attr_done) {
        (void)hipFuncSetAttribute((const void*)gemm256<true, false>,
                                  hipFuncAttributeMaxDynamicSharedMemorySize, 131072);
        attr_done = true;
    }

    char* w = (char*)d_ws;
    uint16_t* X0  = (uint16_t*)w; w += (size_t)M * 1024 * 2;
    uint16_t* X1  = (uint16_t*)w; w += (size_t)M * 2048 * 2;
    uint16_t* X2  = (uint16_t*)w; w += (size_t)M * 2048 * 2;
    uint16_t* W0b = (uint16_t*)w; w += (size_t)2048 * 1024 * 2;
    uint16_t* W1b = (uint16_t*)w; w += (size_t)2048 * 2048 * 2;
    uint16_t* W2b = (uint16_t*)w; w += (size_t)64 * 2048 * 2;

    cvt8<<<M * 1024 / 8 / 256, 256, 0, stream>>>(X, X0, M * 1024);
    cvt8<<<2048 * 1024 / 8 / 256, 256, 0, stream>>>(W0, W0b, 2048 * 1024);
    cvt8<<<2048 * 2048 / 8 / 256, 256, 0, stream>>>(W1, W1b, 2048 * 2048);
    cvt_pad_w2<<<64 * 2048 / 8 / 256, 256, 0, stream>>>(W2, W2b);

    // layer 0: [16384,1024] x [2048,1024]^T -> relu -> bf16; 256x256
    gemm256<true, false><<<dim3((M / 256) * (2048 / 256)), 512, 131072, stream>>>(
        X0, W0b, b0, X1, 1024, 2048, 2048, 2048);
    // layer 1: [16384,2048] x [2048,2048]^T -> relu -> bf16; 256x256
    gemm256<true, false><<<dim3((M / 256) * (2048 / 256)), 512, 131072, stream>>>(
        X1, W1b, b1, X2, 2048, 2048, 2048, 2048);
    // layer 2: [16384,2048] x [64(pad 51),2048]^T -> fp32; 32x64 tiles, 512 blocks
    gemm_bt<1, 2, false, true><<<dim3(M / 32), 256, 0, stream>>>(
        X2, W2b, b2, d_out, M, 64, 2048, 51, 51);
}